// Round 1
// baseline (133.923 us; speedup 1.0000x reference)
//
#include <hip/hip_runtime.h>
#include <hip/hip_bf16.h>

typedef __bf16 bf16x8 __attribute__((ext_vector_type(8)));
typedef float  f32x4  __attribute__((ext_vector_type(4)));

#define NB 16
#define CI 128
#define CO 128
#define HH 64
#define WW 64

// slab: 4 rows x 66 halo-cols x 72 bf16 (64 channels of current half + 8 pad)
// stride 72 bf16 = 144 B = 36 words; 36 % 32 == 4 -> balanced-bank b128 access
#define SROWS 4
#define SCOLS 66
#define SSTR  72

// Pre-swizzle weights into exact A-fragment lane order:
// frag(t, mt): lane l holds A[o = mt*16 + (l&15)][c = (t&3)*32 + (l>>4)*8 + j],
// tap = t>>2 with r = tap%3, s = tap/3  (w[o,c,r,s] pairs with shift dy=s-1, dx=r-1)
__global__ void prep_A(const float* __restrict__ w, __bf16* __restrict__ Ag) {
    int gid  = blockIdx.x * 256 + threadIdx.x;    // [0, 18432)
    int l    = gid & 63;
    int frag = gid >> 6;                          // t*8 + mt
    int mt   = frag & 7;
    int t    = frag >> 3;                         // [0, 36)
    int tap  = t >> 2;
    int r    = tap % 3;
    int s    = tap / 3;
    int o    = mt * 16 + (l & 15);
    int cb   = (t & 3) * 32 + (l >> 4) * 8;
    bf16x8 v;
    #pragma unroll
    for (int j = 0; j < 8; ++j)
        v[j] = (__bf16)w[((o * CI + cb + j) * 3 + r) * 3 + s];
    *(bf16x8*)(Ag + (size_t)gid * 8) = v;
}

// Wsum_u[o] = sum over c of parity u, all 9 taps, of w[o,c,:,:]
__global__ void prep_wsum(const float* __restrict__ w, float* __restrict__ wsum) {
    int tid = threadIdx.x;                        // 256 = 128 o x 2 u
    int u = tid & 1, o = tid >> 1;
    float acc = 0.f;
    for (int c = u; c < CI; c += 2) {
        const float* p = w + (size_t)(o * CI + c) * 9;
        #pragma unroll
        for (int k = 0; k < 9; ++k) acc += p[k];
    }
    wsum[u * CO + o] = acc;
}

__global__ __launch_bounds__(256, 2) void conv_main(
        const float* __restrict__ x,
        const float* __restrict__ bias,
        const float* __restrict__ wsum,
        const __bf16* __restrict__ Ag,
        float* __restrict__ out)
{
    __shared__ __align__(16) __bf16 slab[SROWS * SCOLS * SSTR];  // 38016 B
    __shared__ float Srow[SROWS * SCOLS * 2];                    //  2112 B
    __shared__ float avgl[2 * 64 * 2];                           //  1024 B

    const int tid  = threadIdx.x;
    const int b    = blockIdx.y;
    const int row0 = blockIdx.x * 2;          // output rows row0, row0+1

    const float* xb = x + (size_t)b * CI * HH * WW;

    const int wave = tid >> 6, lane = tid & 63;
    const int wm = wave >> 1, wn = wave & 1;  // wave tile: 64 (M) x 64 (N)
    const int m = lane & 15, q = lane >> 4;

    f32x4 acc[4][4];
    #pragma unroll
    for (int i = 0; i < 4; ++i)
        #pragma unroll
        for (int j = 0; j < 4; ++j)
            acc[i][j] = (f32x4){0.f, 0.f, 0.f, 0.f};

    // B-frag base: slab[(wn + s)*66 + (nt*16 + m + r3)]*72 + cc*32 + q*8
    int bbase[4];
    #pragma unroll
    for (int nt = 0; nt < 4; ++nt)
        bbase[nt] = (wn * SCOLS + nt * 16 + m) * SSTR + q * 8;

    const __bf16* Aw = Ag + ((size_t)(wm * 4) * 64 + lane) * 8;

    for (int half = 0; half < 2; ++half) {
        if (half) __syncthreads();            // slab reused: wait for K-part 0
        // ---- stage 64 channels (edge-clamped halo) ----
        for (int u = tid; u < SROWS * SCOLS * 8; u += 256) {
            int col = u % SCOLS;
            int rc  = u / SCOLS;
            int cg  = rc & 7;
            int r   = rc >> 3;
            int yi  = row0 - 1 + r; yi = yi < 0 ? 0 : (yi > HH - 1 ? HH - 1 : yi);
            int xi  = col - 1;      xi = xi < 0 ? 0 : (xi > WW - 1 ? WW - 1 : xi);
            const float* src = xb + (size_t)(half * 64 + cg * 8) * (HH * WW)
                                  + yi * WW + xi;
            bf16x8 v;
            #pragma unroll
            for (int j = 0; j < 8; ++j)
                v[j] = (__bf16)src[(size_t)j * (HH * WW)];
            *(bf16x8*)(slab + (r * SCOLS + col) * SSTR + cg * 8) = v;
        }
        __syncthreads();
        // ---- per-(row,col) even/odd channel sums over this half ----
        for (int u = tid; u < SROWS * SCOLS; u += 256) {
            const __bf16* p = slab + u * SSTR;
            float se = 0.f, so = 0.f;
            #pragma unroll
            for (int cg = 0; cg < 8; ++cg) {
                bf16x8 v = *(const bf16x8*)(p + cg * 8);
                se += (float)v[0] + (float)v[2] + (float)v[4] + (float)v[6];
                so += (float)v[1] + (float)v[3] + (float)v[5] + (float)v[7];
            }
            if (half) { se += Srow[u * 2 + 0]; so += Srow[u * 2 + 1]; }
            Srow[u * 2 + 0] = se;
            Srow[u * 2 + 1] = so;
        }
        __syncthreads();
        if (half == 1) {
            // ---- 3x3 box mean per (parity, row, col) ----
            int uu  = tid & 1;
            int col = (tid >> 1) & 63;
            int rr  = tid >> 7;
            float ssum = 0.f;
            #pragma unroll
            for (int dy = 0; dy < 3; ++dy)
                #pragma unroll
                for (int dx = 0; dx < 3; ++dx)
                    ssum += Srow[(((rr + dy) * SCOLS) + (col + dx)) * 2 + uu];
            avgl[tid] = ssum * (1.0f / 576.0f);
            __syncthreads();
        }
        // ---- K loop: 9 taps x 2 c-chunks of this half, no inner barriers ----
        #pragma unroll
        for (int tap = 0; tap < 9; ++tap) {
            const int s_ = tap / 3, r3 = tap % 3;
            const int boff0 = (s_ * SCOLS + r3) * SSTR;
            #pragma unroll
            for (int cc = 0; cc < 2; ++cc) {
                const int t    = tap * 4 + half * 2 + cc;
                const int boff = boff0 + cc * 32;
                bf16x8 bfrag[4];
                #pragma unroll
                for (int nt = 0; nt < 4; ++nt)
                    bfrag[nt] = *(const bf16x8*)(slab + bbase[nt] + boff);
                bf16x8 afrag[4];
                #pragma unroll
                for (int i = 0; i < 4; ++i)
                    afrag[i] = *(const bf16x8*)(Aw + (size_t)(t * 8 + i) * 512);
                #pragma unroll
                for (int i = 0; i < 4; ++i)
                    #pragma unroll
                    for (int nt = 0; nt < 4; ++nt)
                        acc[i][nt] = __builtin_amdgcn_mfma_f32_16x16x32_bf16(
                            afrag[i], bfrag[nt], acc[i][nt], 0, 0, 0);
            }
        }
    }

    // ---- epilogue: bias, mean-centering correction, leaky relu, mean re-add ----
    float a0v[4], a1v[4];
    #pragma unroll
    for (int nt = 0; nt < 4; ++nt) {
        int col = nt * 16 + m;
        a0v[nt] = avgl[(wn * 64 + col) * 2 + 0];
        a1v[nt] = avgl[(wn * 64 + col) * 2 + 1];
    }
    float* outb = out + (size_t)b * CO * HH * WW + (size_t)(row0 + wn) * WW;
    #pragma unroll
    for (int i = 0; i < 4; ++i) {
        #pragma unroll
        for (int rg = 0; rg < 4; ++rg) {
            int o = wm * 64 + i * 16 + q * 4 + rg;   // C/D row = (lane>>4)*4 + reg
            float bo = bias[o];
            float w0 = wsum[o];
            float w1 = wsum[CO + o];
            float* po = outb + (size_t)o * (HH * WW);
            #pragma unroll
            for (int nt = 0; nt < 4; ++nt) {
                float v = acc[i][nt][rg] + bo - a0v[nt] * w0 - a1v[nt] * w1;
                v = v > 0.f ? v : 0.01f * v;
                v += (o & 1) ? a1v[nt] : a0v[nt];
                po[nt * 16 + m] = v;                 // C/D col = lane&15
            }
        }
    }
}

extern "C" void kernel_launch(void* const* d_in, const int* in_sizes, int n_in,
                              void* d_out, int out_size, void* d_ws, size_t ws_size,
                              hipStream_t stream) {
    const float* x    = (const float*)d_in[0];
    const float* w    = (const float*)d_in[1];
    const float* bias = (const float*)d_in[2];
    float* out = (float*)d_out;

    __bf16* Ag   = (__bf16*)d_ws;                    // 294912 B, frag-swizzled weights
    float*  wsum = (float*)((char*)d_ws + 294912);   // 1024 B, parity weight sums

    prep_A<<<72, 256, 0, stream>>>(w, Ag);
    prep_wsum<<<1, 256, 0, stream>>>(w, wsum);

    dim3 grid(HH / 2, NB);                           // 32 row-pairs x 16 batches
    conv_main<<<grid, 256, 0, stream>>>(x, bias, wsum, Ag, out);
}

// Round 2
// 104.633 us; speedup vs baseline: 1.2799x; 1.2799x over previous
//
#include <hip/hip_runtime.h>
#include <hip/hip_bf16.h>

typedef __bf16 bf16x8 __attribute__((ext_vector_type(8)));
typedef float  f32x4  __attribute__((ext_vector_type(4)));

#define NB 16
#define CI 128
#define CO 128
#define HH 64
#define WW 64

// slab: 4 rows x 66 halo-cols x 72 bf16 (64 channels of current half + 8 pad)
#define SROWS 4
#define SCOLS 66
#define SSTR  72

// Merged prep. Blocks 0..71: swizzle w into A-fragment lane order.
// Blocks 72..199: wsum for o = blk-72 (parity-split weight sums, block-reduced).
__global__ void prep(const float* __restrict__ w, __bf16* __restrict__ Ag,
                     float* __restrict__ wsum) {
    __shared__ float red[8];
    const int blk = blockIdx.x, tid = threadIdx.x;
    if (blk < 72) {
        int gid  = blk * 256 + tid;                 // [0, 18432)
        int l    = gid & 63;
        int frag = gid >> 6;                        // t*8 + mt
        int mt   = frag & 7;
        int t    = frag >> 3;                       // [0, 36)
        int tap  = t >> 2;
        int r    = tap % 3;
        int s    = tap / 3;
        int o    = mt * 16 + (l & 15);
        int cb   = (t & 3) * 32 + (l >> 4) * 8;
        bf16x8 v;
        #pragma unroll
        for (int j = 0; j < 8; ++j)
            v[j] = (__bf16)w[((o * CI + cb + j) * 3 + r) * 3 + s];
        *(bf16x8*)(Ag + (size_t)gid * 8) = v;
    } else {
        int o = blk - 72;                           // [0, 128)
        const float* p = w + (size_t)o * CI * 9;
        float se = 0.f, so = 0.f;
        for (int idx = tid; idx < CI * 9; idx += 256) {
            int c = idx / 9;
            float v = p[idx];
            if (c & 1) so += v; else se += v;
        }
        #pragma unroll
        for (int off = 32; off; off >>= 1) {
            se += __shfl_down(se, off);
            so += __shfl_down(so, off);
        }
        int wave = tid >> 6, lane = tid & 63;
        if (lane == 0) { red[wave * 2] = se; red[wave * 2 + 1] = so; }
        __syncthreads();
        if (tid == 0) {
            wsum[o]      = red[0] + red[2] + red[4] + red[6];
            wsum[CO + o] = red[1] + red[3] + red[5] + red[7];
        }
    }
}

__global__ __launch_bounds__(512, 4) void conv_main(
        const float* __restrict__ x,
        const float* __restrict__ bias,
        const float* __restrict__ wsum,
        const __bf16* __restrict__ Ag,
        float* __restrict__ out)
{
    __shared__ __align__(16) __bf16 slab[SROWS * SCOLS * SSTR];  // 38016 B
    __shared__ float Srow[SROWS * SCOLS * 2];                    //  2112 B
    __shared__ float avgl[2 * 64 * 2];                           //  1024 B

    const int tid  = threadIdx.x;
    const int b    = blockIdx.y;
    const int row0 = blockIdx.x * 2;          // output rows row0, row0+1

    const float* xb = x + (size_t)b * CI * HH * WW;

    const int wave = tid >> 6, lane = tid & 63;
    const int wm = wave >> 1, wn = wave & 1;  // wave tile: 32 (M) x 64 (N)
    const int m = lane & 15, q = lane >> 4;

    f32x4 acc[2][4];
    #pragma unroll
    for (int i = 0; i < 2; ++i)
        #pragma unroll
        for (int j = 0; j < 4; ++j)
            acc[i][j] = (f32x4){0.f, 0.f, 0.f, 0.f};

    int bbase[4];
    #pragma unroll
    for (int nt = 0; nt < 4; ++nt)
        bbase[nt] = (wn * SCOLS + nt * 16 + m) * SSTR + q * 8;

    // A frag f = t*8 + (wm*2 + i): addr = f*512 + lane*8
    const __bf16* Aw = Ag + (size_t)(wm * 2) * 512 + (size_t)lane * 8;

    for (int half = 0; half < 2; ++half) {
        if (half) __syncthreads();            // slab reused: wait for K-part 0
        // ---- stage 64 channels (edge-clamped halo) ----
        for (int u = tid; u < SROWS * SCOLS * 8; u += 512) {
            int col = u % SCOLS;
            int rc  = u / SCOLS;
            int cg  = rc & 7;
            int r   = rc >> 3;
            int yi  = row0 - 1 + r; yi = yi < 0 ? 0 : (yi > HH - 1 ? HH - 1 : yi);
            int xi  = col - 1;      xi = xi < 0 ? 0 : (xi > WW - 1 ? WW - 1 : xi);
            const float* src = xb + (size_t)(half * 64 + cg * 8) * (HH * WW)
                                  + yi * WW + xi;
            bf16x8 v;
            #pragma unroll
            for (int j = 0; j < 8; ++j)
                v[j] = (__bf16)src[(size_t)j * (HH * WW)];
            *(bf16x8*)(slab + (r * SCOLS + col) * SSTR + cg * 8) = v;
        }
        __syncthreads();
        // ---- per-(row,col) even/odd channel sums over this half ----
        for (int u = tid; u < SROWS * SCOLS; u += 512) {
            const __bf16* p = slab + u * SSTR;
            float se = 0.f, so = 0.f;
            #pragma unroll
            for (int cg = 0; cg < 8; ++cg) {
                bf16x8 v = *(const bf16x8*)(p + cg * 8);
                se += (float)v[0] + (float)v[2] + (float)v[4] + (float)v[6];
                so += (float)v[1] + (float)v[3] + (float)v[5] + (float)v[7];
            }
            if (half) { se += Srow[u * 2 + 0]; so += Srow[u * 2 + 1]; }
            Srow[u * 2 + 0] = se;
            Srow[u * 2 + 1] = so;
        }
        __syncthreads();
        if (half == 1) {
            // ---- 3x3 box mean per (parity, row, col) ----
            if (tid < 256) {
                int uu  = tid & 1;
                int col = (tid >> 1) & 63;
                int rr  = tid >> 7;
                float ssum = 0.f;
                #pragma unroll
                for (int dy = 0; dy < 3; ++dy)
                    #pragma unroll
                    for (int dx = 0; dx < 3; ++dx)
                        ssum += Srow[(((rr + dy) * SCOLS) + (col + dx)) * 2 + uu];
                avgl[tid] = ssum * (1.0f / 576.0f);
            }
            __syncthreads();
        }
        // ---- K loop: 9 taps x 2 c-chunks of this half, no inner barriers ----
        #pragma unroll
        for (int tap = 0; tap < 9; ++tap) {
            const int s_ = tap / 3, r3 = tap % 3;
            const int boff0 = (s_ * SCOLS + r3) * SSTR;
            #pragma unroll
            for (int cc = 0; cc < 2; ++cc) {
                const int t    = tap * 4 + half * 2 + cc;
                const int boff = boff0 + cc * 32;
                bf16x8 bfrag[4];
                #pragma unroll
                for (int nt = 0; nt < 4; ++nt)
                    bfrag[nt] = *(const bf16x8*)(slab + bbase[nt] + boff);
                bf16x8 afrag[2];
                #pragma unroll
                for (int i = 0; i < 2; ++i)
                    afrag[i] = *(const bf16x8*)(Aw + (size_t)t * 4096 + i * 512);
                #pragma unroll
                for (int i = 0; i < 2; ++i)
                    #pragma unroll
                    for (int nt = 0; nt < 4; ++nt)
                        acc[i][nt] = __builtin_amdgcn_mfma_f32_16x16x32_bf16(
                            afrag[i], bfrag[nt], acc[i][nt], 0, 0, 0);
            }
        }
    }

    // ---- epilogue: bias, mean-centering correction, leaky relu, mean re-add ----
    float a0v[4], a1v[4];
    #pragma unroll
    for (int nt = 0; nt < 4; ++nt) {
        int col = nt * 16 + m;
        a0v[nt] = avgl[(wn * 64 + col) * 2 + 0];
        a1v[nt] = avgl[(wn * 64 + col) * 2 + 1];
    }
    float* outb = out + (size_t)b * CO * HH * WW + (size_t)(row0 + wn) * WW;
    #pragma unroll
    for (int i = 0; i < 2; ++i) {
        #pragma unroll
        for (int rg = 0; rg < 4; ++rg) {
            int o = wm * 32 + i * 16 + q * 4 + rg;   // C/D row = (lane>>4)*4 + reg
            float bo = bias[o];
            float w0 = wsum[o];
            float w1 = wsum[CO + o];
            float* po = outb + (size_t)o * (HH * WW);
            #pragma unroll
            for (int nt = 0; nt < 4; ++nt) {
                float v = acc[i][nt][rg] + bo - a0v[nt] * w0 - a1v[nt] * w1;
                v = v > 0.f ? v : 0.01f * v;
                v += (o & 1) ? a1v[nt] : a0v[nt];
                po[nt * 16 + m] = v;                 // C/D col = lane&15
            }
        }
    }
}

extern "C" void kernel_launch(void* const* d_in, const int* in_sizes, int n_in,
                              void* d_out, int out_size, void* d_ws, size_t ws_size,
                              hipStream_t stream) {
    const float* x    = (const float*)d_in[0];
    const float* w    = (const float*)d_in[1];
    const float* bias = (const float*)d_in[2];
    float* out = (float*)d_out;

    __bf16* Ag   = (__bf16*)d_ws;                    // 294912 B, frag-swizzled weights
    float*  wsum = (float*)((char*)d_ws + 294912);   // 1024 B, parity weight sums

    prep<<<200, 256, 0, stream>>>(w, Ag, wsum);

    dim3 grid(HH / 2, NB);                           // 32 row-pairs x 16 batches
    conv_main<<<grid, 512, 0, stream>>>(x, bias, wsum, Ag, out);
}